// Round 1
// baseline (351.696 us; speedup 1.0000x reference)
//
#include <hip/hip_runtime.h>
#include <hip/hip_bf16.h>
#include <stdint.h>

// Problem constants
#define Bq 1024
#define Dq 512
#define Nq 16
#define Hq 512
#define Mq (Bq*Nq)   // 16384

typedef short v8s __attribute__((ext_vector_type(8)));
typedef float v4f __attribute__((ext_vector_type(4)));
typedef int   v4i __attribute__((ext_vector_type(4)));

__device__ __forceinline__ unsigned short f2bf(float f) {
  union { float f; unsigned u; } v; v.f = f;
  return (unsigned short)((v.u + 0x7fffu + ((v.u >> 16) & 1u)) >> 16);
}

// Xb[b*16+n][d] = bf16(x[b][d][n])
__global__ void k_transpose_x(const float* __restrict__ x, unsigned short* __restrict__ xb) {
  __shared__ float lds[Dq][Nq + 1];
  const int b = blockIdx.x;
  const float* xi = x + (size_t)b * Dq * Nq;
  const int t = threadIdx.x;
  for (int p = 0; p < (Dq*Nq)/256; ++p) {
    int i = t + p*256;
    lds[i >> 4][i & (Nq-1)] = xi[i];
  }
  __syncthreads();
  unsigned short* o = xb + (size_t)b * Nq * Dq;
  for (int p = 0; p < (Dq*Nq)/256; ++p) {
    int i = t + p*256;
    o[i] = f2bf(lds[i & (Dq-1)][i >> 9]);   // i = n*512 + d
  }
}

// out[z][c][r] = bf16(in[z][r][c]) for R x C matrices (R=C=512 here)
__global__ void k_transpose_w(const float* __restrict__ in, unsigned short* __restrict__ out,
                              int R, int C) {
  __shared__ float tile[32][33];
  const int z = blockIdx.z;
  in  += (size_t)z * R * C;
  out += (size_t)z * R * C;
  const int tx = threadIdx.x, ty = threadIdx.y;  // (32,8)
  const int c0 = blockIdx.x * 32, r0 = blockIdx.y * 32;
#pragma unroll
  for (int j = 0; j < 4; ++j)
    tile[ty + j*8][tx] = in[(size_t)(r0 + ty + j*8) * C + c0 + tx];
  __syncthreads();
#pragma unroll
  for (int j = 0; j < 4; ++j) {
    int c = c0 + ty + j*8;   // output row (input col)
    int r = r0 + tx;         // output col (input row)
    out[(size_t)c * R + r] = f2bf(tile[tx][ty + j*8]);
  }
}

// 128x128 tile MFMA GEMM, K=512, Nout=512, A: MxK bf16 row-major, Bt: Nout x K bf16.
// MODE 0: out = lrelu(A@B + bias) as bf16 (row permuted to m = (r&15)*1024 + (r>>4) if permute).
// MODE 1: per-head (z): atomicAdd into FL[m][z] of sum_h lrelu(A@B + bc1[z])*Wc2[z][h].
template<int MODE>
__global__ __launch_bounds__(256)
void k_gemm(const unsigned short* __restrict__ A,
            const unsigned short* __restrict__ Bt,
            const float* __restrict__ bias,
            void* __restrict__ out_,
            const float* __restrict__ w2,
            int permute) {
  constexpr int BM = 128, BN = 128, BK = 32, KD = 512;
  __shared__ __align__(16) unsigned short As[BM][BK + 8];  // +16B pad: 2-way banks (free)
  __shared__ __align__(16) unsigned short Bs[BN][BK + 8];

  const int t = threadIdx.x;
  const int wave = t >> 6, lane = t & 63;
  const int wr = wave >> 1, wc = wave & 1;
  const int quad = lane >> 4, l16 = lane & 15;
  const int bm = blockIdx.x * BM, bn = blockIdx.y * BN;
  const int z = blockIdx.z;

  const unsigned short* Bz = Bt + (size_t)z * KD * 512;
  const float* biasz = bias + (size_t)z * 512;

  v4f acc[4][4] = {};

  for (int kt = 0; kt < KD / BK; ++kt) {
#pragma unroll
    for (int p = 0; p < 2; ++p) {
      int c = t + p * 256;
      int row = c >> 2, kc = (c & 3) * 8;
      *(v4i*)&As[row][kc] = *(const v4i*)&A [(size_t)(bm + row) * KD + kt*BK + kc];
      *(v4i*)&Bs[row][kc] = *(const v4i*)&Bz[(size_t)(bn + row) * KD + kt*BK + kc];
    }
    __syncthreads();
    v8s af[4], bf[4];
#pragma unroll
    for (int mi = 0; mi < 4; ++mi)
      af[mi] = *(const v8s*)&As[wr*64 + mi*16 + l16][quad*8];
#pragma unroll
    for (int ni = 0; ni < 4; ++ni)
      bf[ni] = *(const v8s*)&Bs[wc*64 + ni*16 + l16][quad*8];
#pragma unroll
    for (int mi = 0; mi < 4; ++mi)
#pragma unroll
      for (int ni = 0; ni < 4; ++ni)
        acc[mi][ni] = __builtin_amdgcn_mfma_f32_16x16x32_bf16(af[mi], bf[ni], acc[mi][ni], 0, 0, 0);
    __syncthreads();
  }

  if (MODE == 0) {
    unsigned short* O = (unsigned short*)out_;
#pragma unroll
    for (int mi = 0; mi < 4; ++mi) {
#pragma unroll
      for (int r = 0; r < 4; ++r) {
        int grow = bm + wr*64 + mi*16 + quad*4 + r;
        int orow = permute ? ((grow & 15) * Bq + (grow >> 4)) : grow;
#pragma unroll
        for (int ni = 0; ni < 4; ++ni) {
          int col = bn + wc*64 + ni*16 + l16;
          float v = acc[mi][ni][r] + biasz[col];
          v = v >= 0.f ? v : 0.1f * v;
          O[(size_t)orow * 512 + col] = f2bf(v);
        }
      }
    }
  } else {
    float* FL = (float*)out_;             // [Mq][Nq]
    const float* w2z = w2 + (size_t)z * 512;
#pragma unroll
    for (int mi = 0; mi < 4; ++mi) {
#pragma unroll
      for (int r = 0; r < 4; ++r) {
        float s = 0.f;
#pragma unroll
        for (int ni = 0; ni < 4; ++ni) {
          int col = bn + wc*64 + ni*16 + l16;
          float v = acc[mi][ni][r] + biasz[col];
          v = v >= 0.f ? v : 0.1f * v;
          s += v * w2z[col];
        }
        // reduce the 16 lanes of this quad (same output row)
#pragma unroll
        for (int off = 1; off < 16; off <<= 1)
          s += __shfl_xor(s, off, 64);
        if (l16 == 0) {
          int grow = bm + wr*64 + mi*16 + quad*4 + r;
          atomicAdd(&FL[(size_t)grow * Nq + z], s);
        }
      }
    }
  }
}

// full_out[m][n] = FL[m][n] + bc2[n]; out[b][n] = sigmoid(full_out[n*B+b][n])
__global__ void k_final(const float* __restrict__ fl, const float* __restrict__ bc2,
                        float* __restrict__ out) {
  int i = blockIdx.x * 256 + threadIdx.x;   // i over Mq*Nq
  int m = i >> 4, n = i & 15;
  float v = fl[i] + bc2[n];
  out[Mq + i] = v;                           // full_out, offset by |out| = 16384
  if (n == (m >> 10)) {                      // diagonal: m = n*B + b
    int b = m & (Bq - 1);
    out[b * Nq + n] = 1.f / (1.f + __expf(-v));
  }
}

extern "C" void kernel_launch(void* const* d_in, const int* in_sizes, int n_in,
                              void* d_out, int out_size, void* d_ws, size_t ws_size,
                              hipStream_t stream) {
  (void)in_sizes; (void)n_in; (void)out_size; (void)ws_size;
  const float* x   = (const float*)d_in[0];
  const float* Ws1 = (const float*)d_in[1];
  const float* bs1 = (const float*)d_in[2];
  const float* Ws2 = (const float*)d_in[3];
  const float* bs2 = (const float*)d_in[4];
  const float* Wc1 = (const float*)d_in[5];
  const float* bc1 = (const float*)d_in[6];
  const float* Wc2 = (const float*)d_in[7];
  const float* bc2 = (const float*)d_in[8];

  char* ws = (char*)d_ws;
  unsigned short* Xb   = (unsigned short*)(ws);                          // 16 MB
  unsigned short* Hbuf = (unsigned short*)(ws + (size_t)16*1024*1024);   // 16 MB
  unsigned short* Sm   = (unsigned short*)(ws + (size_t)32*1024*1024);   // 16 MB
  unsigned short* Ws1t = (unsigned short*)(ws + (size_t)48*1024*1024);   // 512 KB
  unsigned short* Ws2t = (unsigned short*)(ws + (size_t)48*1024*1024 + 512*1024);
  unsigned short* Wc1t = (unsigned short*)(ws + (size_t)49*1024*1024);   // 8 MB
  float*          FL   = (float*)         (ws + (size_t)57*1024*1024);   // 1 MB

  hipMemsetAsync(FL, 0, (size_t)Mq * Nq * sizeof(float), stream);

  k_transpose_x<<<Bq, 256, 0, stream>>>(x, Xb);
  dim3 tb(32, 8);
  k_transpose_w<<<dim3(16,16,1),  tb, 0, stream>>>(Ws1, Ws1t, 512, 512);
  k_transpose_w<<<dim3(16,16,1),  tb, 0, stream>>>(Ws2, Ws2t, 512, 512);
  k_transpose_w<<<dim3(16,16,16), tb, 0, stream>>>(Wc1, Wc1t, 512, 512);

  // shared MLP: H = lrelu(Xb@Ws1+bs1); Sm = lrelu(H@Ws2+bs2) in m = n*B+b row order
  k_gemm<0><<<dim3(128,4,1), 256, 0, stream>>>(Xb,   Ws1t, bs1, Hbuf, nullptr, 0);
  k_gemm<0><<<dim3(128,4,1), 256, 0, stream>>>(Hbuf, Ws2t, bs2, Sm,   nullptr, 1);
  // fused per-head GEMM + H-reduction into FL
  k_gemm<1><<<dim3(128,4,16), 256, 0, stream>>>(Sm, Wc1t, bc1, FL, Wc2, 0);

  k_final<<<(Mq*Nq)/256, 256, 0, stream>>>(FL, bc2, (float*)d_out);
}

// Round 2
// 334.859 us; speedup vs baseline: 1.0503x; 1.0503x over previous
//
#include <hip/hip_runtime.h>
#include <hip/hip_bf16.h>
#include <stdint.h>

// Problem constants
#define Bq 1024
#define Dq 512
#define Nq 16
#define Hq 512
#define Mq (Bq*Nq)   // 16384

typedef short v8s __attribute__((ext_vector_type(8)));
typedef float v4f __attribute__((ext_vector_type(4)));
typedef int   v4i __attribute__((ext_vector_type(4)));

typedef __attribute__((address_space(3))) unsigned int as3_u32;
typedef __attribute__((address_space(1))) const unsigned int as1_u32;

__device__ __forceinline__ unsigned short f2bf(float f) {
  union { float f; unsigned u; } v; v.f = f;
  return (unsigned short)((v.u + 0x7fffu + ((v.u >> 16) & 1u)) >> 16);
}

// Xb[b*16+n][d] = bf16(x[b][d][n])
__global__ void k_transpose_x(const float* __restrict__ x, unsigned short* __restrict__ xb) {
  __shared__ float lds[Dq][Nq + 1];
  const int b = blockIdx.x;
  const float* xi = x + (size_t)b * Dq * Nq;
  const int t = threadIdx.x;
  for (int p = 0; p < (Dq*Nq)/256; ++p) {
    int i = t + p*256;
    lds[i >> 4][i & (Nq-1)] = xi[i];
  }
  __syncthreads();
  unsigned short* o = xb + (size_t)b * Nq * Dq;
  for (int p = 0; p < (Dq*Nq)/256; ++p) {
    int i = t + p*256;
    o[i] = f2bf(lds[i & (Dq-1)][i >> 9]);   // i = n*512 + d
  }
}

// One dispatch for all weight transposes: z=0 -> Ws1, z=1 -> Ws2, z>=2 -> Wc1[z-2]
// out[z][c][r] = bf16(in[z][r][c]), 512x512 each
__global__ void k_transpose_w(const float* __restrict__ Ws1, const float* __restrict__ Ws2,
                              const float* __restrict__ Wc1,
                              unsigned short* __restrict__ Ws1t, unsigned short* __restrict__ Ws2t,
                              unsigned short* __restrict__ Wc1t) {
  __shared__ float tile[32][33];
  const int z = blockIdx.z;
  const float* in;
  unsigned short* out;
  if (z == 0)      { in = Ws1; out = Ws1t; }
  else if (z == 1) { in = Ws2; out = Ws2t; }
  else             { in = Wc1 + (size_t)(z-2) * 512 * 512; out = Wc1t + (size_t)(z-2) * 512 * 512; }
  const int tx = threadIdx.x, ty = threadIdx.y;  // (32,8)
  const int c0 = blockIdx.x * 32, r0 = blockIdx.y * 32;
#pragma unroll
  for (int j = 0; j < 4; ++j)
    tile[ty + j*8][tx] = in[(size_t)(r0 + ty + j*8) * 512 + c0 + tx];
  __syncthreads();
#pragma unroll
  for (int j = 0; j < 4; ++j) {
    int c = c0 + ty + j*8;   // output row (input col)
    int r = r0 + tx;         // output col (input row)
    out[(size_t)c * 512 + r] = f2bf(tile[tx][ty + j*8]);
  }
}

// 128x128 tile MFMA GEMM, K=512, Nout=512, A: MxK bf16 row-major, Bt: Nout x K bf16.
// Staging via global_load_lds width=16 (wave-uniform LDS base + lane*16 — no padding).
// Bank-conflict fix: 16B chunk c of row r stored at slot c ^ ((r>>1)&3) (XOR swizzle);
// read side fetches slot quad ^ ((r>>1)&3) -> 2-way bank aliasing (free, m136).
// MODE 0: out = lrelu(A@B + bias) as bf16 (row permuted to m = (r&15)*1024 + (r>>4) if permute).
// MODE 1: per-head (z): atomicAdd into FL[m][z] of sum_h lrelu(A@B + bc1[z])*Wc2[z][h].
template<int MODE>
__global__ __launch_bounds__(256)
void k_gemm(const unsigned short* __restrict__ A,
            const unsigned short* __restrict__ Bt,
            const float* __restrict__ bias,
            void* __restrict__ out_,
            const float* __restrict__ w2,
            int permute) {
  constexpr int BM = 128, BN = 128, BK = 32, KD = 512;
  __shared__ __align__(16) unsigned short As[BM][BK];  // 8 KB, unpadded (global_load_lds)
  __shared__ __align__(16) unsigned short Bs[BN][BK];

  const int t = threadIdx.x;
  const int wave = t >> 6, lane = t & 63;
  const int wr = wave >> 1, wc = wave & 1;
  const int quad = lane >> 4, l16 = lane & 15;
  const int bm = blockIdx.x * BM, bn = blockIdx.y * BN;
  const int z = blockIdx.z;

  const unsigned short* Bz = Bt + (size_t)z * KD * 512;
  const float* biasz = bias + (size_t)z * 512;

  // Staging geometry: each global_load_lds_dwordx4 covers 16 rows x 64 B.
  // wave w, p in {0,1}: rows r0 = (w*2+p)*16 .. +15; lane i -> row r0+(i>>2), slot i&3.
  // Global chunk for lane = (i&3) ^ ((row>>1)&3)  [swizzled storage]
  const int srow0 = wave * 32;                 // rows covered by this wave: srow0 .. srow0+31
  const int lrow = lane >> 2;                  // 0..15 within a 16-row chunk
  const int lslot = lane & 3;

  v4f acc[4][4] = {};

  for (int kt = 0; kt < KD / BK; ++kt) {
#pragma unroll
    for (int p = 0; p < 2; ++p) {
      int r0 = srow0 + p * 16;
      int row = r0 + lrow;
      int cg = lslot ^ ((row >> 1) & 3);       // swizzled global chunk
      const unsigned short* ga = &A [(size_t)(bm + row) * KD + kt*BK + cg*8];
      const unsigned short* gb = &Bz[(size_t)(bn + row) * KD + kt*BK + cg*8];
      __builtin_amdgcn_global_load_lds((as1_u32*)ga, (as3_u32*)&As[r0][0], 16, 0, 0);
      __builtin_amdgcn_global_load_lds((as1_u32*)gb, (as3_u32*)&Bs[r0][0], 16, 0, 0);
    }
    __syncthreads();
    v8s af[4], bf[4];
#pragma unroll
    for (int mi = 0; mi < 4; ++mi) {
      int ra = wr*64 + mi*16 + l16;
      af[mi] = *(const v8s*)&As[ra][(quad ^ ((ra >> 1) & 3)) * 8];
    }
#pragma unroll
    for (int ni = 0; ni < 4; ++ni) {
      int rb = wc*64 + ni*16 + l16;
      bf[ni] = *(const v8s*)&Bs[rb][(quad ^ ((rb >> 1) & 3)) * 8];
    }
#pragma unroll
    for (int mi = 0; mi < 4; ++mi)
#pragma unroll
      for (int ni = 0; ni < 4; ++ni)
        acc[mi][ni] = __builtin_amdgcn_mfma_f32_16x16x32_bf16(af[mi], bf[ni], acc[mi][ni], 0, 0, 0);
    __syncthreads();
  }

  if (MODE == 0) {
    unsigned short* O = (unsigned short*)out_;
#pragma unroll
    for (int mi = 0; mi < 4; ++mi) {
#pragma unroll
      for (int r = 0; r < 4; ++r) {
        int grow = bm + wr*64 + mi*16 + quad*4 + r;
        int orow = permute ? ((grow & 15) * Bq + (grow >> 4)) : grow;
#pragma unroll
        for (int ni = 0; ni < 4; ++ni) {
          int col = bn + wc*64 + ni*16 + l16;
          float v = acc[mi][ni][r] + biasz[col];
          v = v >= 0.f ? v : 0.1f * v;
          O[(size_t)orow * 512 + col] = f2bf(v);
        }
      }
    }
  } else {
    float* FL = (float*)out_;             // [Mq][Nq]
    const float* w2z = w2 + (size_t)z * 512;
#pragma unroll
    for (int mi = 0; mi < 4; ++mi) {
#pragma unroll
      for (int r = 0; r < 4; ++r) {
        float s = 0.f;
#pragma unroll
        for (int ni = 0; ni < 4; ++ni) {
          int col = bn + wc*64 + ni*16 + l16;
          float v = acc[mi][ni][r] + biasz[col];
          v = v >= 0.f ? v : 0.1f * v;
          s += v * w2z[col];
        }
        // reduce the 16 lanes of this quad (same output row)
#pragma unroll
        for (int off = 1; off < 16; off <<= 1)
          s += __shfl_xor(s, off, 64);
        if (l16 == 0) {
          int grow = bm + wr*64 + mi*16 + quad*4 + r;
          atomicAdd(&FL[(size_t)grow * Nq + z], s);
        }
      }
    }
  }
}

// full_out[m][n] = FL[m][n] + bc2[n]; out[b][n] = sigmoid(full_out[n*B+b][n])
__global__ void k_final(const float* __restrict__ fl, const float* __restrict__ bc2,
                        float* __restrict__ out) {
  int i = blockIdx.x * 256 + threadIdx.x;   // i over Mq*Nq
  int m = i >> 4, n = i & 15;
  float v = fl[i] + bc2[n];
  out[Mq + i] = v;                           // full_out, offset by |out| = 16384
  if (n == (m >> 10)) {                      // diagonal: m = n*B + b
    int b = m & (Bq - 1);
    out[b * Nq + n] = 1.f / (1.f + __expf(-v));
  }
}

extern "C" void kernel_launch(void* const* d_in, const int* in_sizes, int n_in,
                              void* d_out, int out_size, void* d_ws, size_t ws_size,
                              hipStream_t stream) {
  (void)in_sizes; (void)n_in; (void)out_size; (void)ws_size;
  const float* x   = (const float*)d_in[0];
  const float* Ws1 = (const float*)d_in[1];
  const float* bs1 = (const float*)d_in[2];
  const float* Ws2 = (const float*)d_in[3];
  const float* bs2 = (const float*)d_in[4];
  const float* Wc1 = (const float*)d_in[5];
  const float* bc1 = (const float*)d_in[6];
  const float* Wc2 = (const float*)d_in[7];
  const float* bc2 = (const float*)d_in[8];

  char* ws = (char*)d_ws;
  unsigned short* Xb   = (unsigned short*)(ws);                          // 16 MB
  unsigned short* Hbuf = (unsigned short*)(ws + (size_t)16*1024*1024);   // 16 MB
  unsigned short* Sm   = (unsigned short*)(ws + (size_t)32*1024*1024);   // 16 MB
  unsigned short* Ws1t = (unsigned short*)(ws + (size_t)48*1024*1024);   // 512 KB
  unsigned short* Ws2t = (unsigned short*)(ws + (size_t)48*1024*1024 + 512*1024);
  unsigned short* Wc1t = (unsigned short*)(ws + (size_t)49*1024*1024);   // 8 MB
  float*          FL   = (float*)         (ws + (size_t)57*1024*1024);   // 1 MB

  hipMemsetAsync(FL, 0, (size_t)Mq * Nq * sizeof(float), stream);

  k_transpose_x<<<Bq, 256, 0, stream>>>(x, Xb);
  k_transpose_w<<<dim3(16,16,18), dim3(32,8), 0, stream>>>(Ws1, Ws2, Wc1, Ws1t, Ws2t, Wc1t);

  // shared MLP: H = lrelu(Xb@Ws1+bs1); Sm = lrelu(H@Ws2+bs2) in m = n*B+b row order
  k_gemm<0><<<dim3(128,4,1), 256, 0, stream>>>(Xb,   Ws1t, bs1, Hbuf, nullptr, 0);
  k_gemm<0><<<dim3(128,4,1), 256, 0, stream>>>(Hbuf, Ws2t, bs2, Sm,   nullptr, 1);
  // fused per-head GEMM + H-reduction into FL
  k_gemm<1><<<dim3(128,4,16), 256, 0, stream>>>(Sm, Wc1t, bc1, FL, Wc2, 0);

  k_final<<<(Mq*Nq)/256, 256, 0, stream>>>(FL, bc2, (float*)d_out);
}